// Round 11
// baseline (412.737 us; speedup 1.0000x reference)
//
#include <hip/hip_runtime.h>

#define HH 320
#define WW 320
#define BB 8
static constexpr float EPS = 1e-5f;

typedef __attribute__((ext_vector_type(8))) short bf16x8;
typedef __attribute__((ext_vector_type(4))) float f32x4;

__device__ inline float bf2f(unsigned short u) {
    union { unsigned int i; float f; } v; v.i = ((unsigned int)u) << 16; return v.f;
}
__device__ inline unsigned short f2bf(float f) {
    union { float f; unsigned int i; } v; v.f = f;
    unsigned int r = v.i + 0x7fffu + ((v.i >> 16) & 1u);
    return (unsigned short)(r >> 16);
}
__device__ inline unsigned int cvtpk(float a, float b) {   // lo16=bf16(a), hi16=bf16(b)
    unsigned int r;
    asm volatile("v_cvt_pk_bf16_f32 %0, %1, %2" : "=v"(r) : "v"(a), "v"(b));
    return r;
}
__device__ inline void glds16(const void* g, void* l) {
    __builtin_amdgcn_global_load_lds(
        (const __attribute__((address_space(1))) unsigned int*)g,
        (__attribute__((address_space(3))) unsigned int*)l, 16, 0, 0);
}

// ---------------- NCHW fp32 -> NHWC bf16 (CIN=32) ----------------
__global__ __launch_bounds__(256) void prep_hwc(const float* __restrict__ in,
                                                unsigned short* __restrict__ out)
{
    __shared__ float sT[32][65];
    const int tid = threadIdx.x;
    const int x0  = blockIdx.x * 64;
    const int y   = blockIdx.y;
    const int b   = blockIdx.z;
    for (int e = tid; e < 32 * 64; e += 256) {
        int c = e >> 6, x = e & 63;
        sT[c][x] = in[(((size_t)(b * 32 + c) * HH) + y) * WW + x0 + x];
    }
    __syncthreads();
    for (int e = tid; e < 64 * 32; e += 256) {
        int x = e >> 5, c = e & 31;
        out[((((size_t)b * HH + y) * WW) + x0 + x) * 32 + c] = f2bf(sT[c][x]);
    }
}

// ------ weights OIHW fp32 -> bank-swizzled bf16 glds-ready images ------
// unit i = icc*2304 + kk*256 + oc*4 + s; content j = w[oc][icc*32 + (s^swz(oc))*8 + j][kk]
__global__ __launch_bounds__(256) void wprep_swz(const float* __restrict__ w1,
                                                 const float* __restrict__ w2,
                                                 unsigned short* __restrict__ wt1,
                                                 unsigned short* __restrict__ wt2)
{
    int i = blockIdx.x * 256 + threadIdx.x;
    if (i < 2304) {
        int s = i & 3, oc = (i >> 2) & 63, kk = i >> 8;
        int icq = s ^ ((oc >> 1) & 3);
        const float* src = w1 + ((size_t)oc * 32 + icq * 8) * 9 + kk;
        unsigned short pk[8];
#pragma unroll
        for (int j = 0; j < 8; ++j) pk[j] = f2bf(src[j * 9]);
        *(bf16x8*)&wt1[(size_t)i * 8] = *(bf16x8*)pk;
    }
    if (i < 4608) {
        int icc = i / 2304, u = i - icc * 2304;
        int s = u & 3, oc = (u >> 2) & 63, kk = u >> 8;
        int icq = s ^ ((oc >> 1) & 3);
        const float* src = w2 + ((size_t)oc * 64 + icc * 32 + icq * 8) * 9 + kk;
        unsigned short pk[8];
#pragma unroll
        for (int j = 0; j < 8; ++j) pk[j] = f2bf(src[j * 9]);
        *(bf16x8*)&wt2[(size_t)i * 8] = *(bf16x8*)pk;
    }
}

// ------ fold conv1 InstanceNorm scale into conv2 weights (per batch) ------
// wt2b[b] = bf16( w2 * r[b,c] );  bias2b[b][o] = b2[o] - sum_{c,k} bf2f(w') * mu_bf[b,c]
__global__ __launch_bounds__(256) void wfold(const unsigned short* __restrict__ wt2,
                                             const float* __restrict__ b2,
                                             const float2* __restrict__ stats1,
                                             unsigned short* __restrict__ wt2b,
                                             float* __restrict__ bias2b)
{
    __shared__ float sMu[64], sR[64];
    __shared__ float sBias[256];
    const int b = blockIdx.x, tid = threadIdx.x;
    if (tid < 64) {
        float2 ms = stats1[b * 64 + tid];
        sMu[tid] = bf2f(f2bf(ms.x));     // mu_bf, used consistently with staged pads
        sR[tid]  = ms.y;
    }
    __syncthreads();
    const int oc = tid & 63, rep = tid >> 6;
    float bsum = 0.f;
    for (int cs = rep * 2; cs < rep * 2 + 2; ++cs) {
        int icc = cs >> 2, s = cs & 3;
        int icq = s ^ ((oc >> 1) & 3);
        for (int kk = 0; kk < 9; ++kk) {
            size_t u = (size_t)icc * 2304 + kk * 256 + oc * 4 + s;
            bf16x8 v = *(const bf16x8*)&wt2[u * 8];
            unsigned short o8[8];
#pragma unroll
            for (int j = 0; j < 8; ++j) {
                int ic = icc * 32 + icq * 8 + j;
                unsigned short wb = f2bf(bf2f(((unsigned short*)&v)[j]) * sR[ic]);
                o8[j] = wb;
                bsum += bf2f(wb) * sMu[ic];
            }
            *(bf16x8*)&wt2b[((size_t)b * 4608 + u) * 8] = *(bf16x8*)o8;
        }
    }
    sBias[tid] = bsum;
    __syncthreads();
    if (tid < 64) {
        float t = sBias[tid] + sBias[tid + 64] + sBias[tid + 128] + sBias[tid + 192];
        bias2b[b * 64 + tid] = b2[tid] - t;
    }
}

// ---------------- implicit-GEMM conv 3x3 via MFMA, 16-wave occupancy ----------------
// Block: 4 waves, wave w owns output row y0+w. Tile: 4 rows x 64 px x 64 oc.
// sW staged per ky-row (3 kk = 12.3 KB) -> LDS ~38 KB -> 4 blocks/CU.
// NORM=0 (conv1): sA via glds (pre-swizzled source), zero pads.
// NORM=1 (conv2): sA = bf16(max(h, mu_bf)) (scale folded into wt2b), pads = mu_bf.
// Output: D[oc][px] (swapped mfma operands), 8B NHWC bf16 stores.
template<int CIN, int NORM>
__global__ __launch_bounds__(256, 4) void conv_mfma(
    const unsigned short* __restrict__ in_hwc,   // [B][H][W][CIN] bf16
    const float2* __restrict__ stats_in,         // [B*64] (NORM)
    const unsigned short* __restrict__ wt,       // image; per-batch when NORM
    const float* __restrict__ bias,              // [64]; per-batch when NORM
    unsigned short* __restrict__ out_hwc,        // [B][H][W][64] bf16
    float2* __restrict__ partials)               // [B*400][64]
{
    constexpr int ICC = CIN / 32;

    __shared__ __align__(16) char smem[38912];
    unsigned short* sA    = (unsigned short*)smem;              // 25344 B
    unsigned short* sW    = (unsigned short*)(smem + 25344);    // 12288 B  [kx][oc][s]
    float*          sMaxMu= (float*)(smem + 37632);             // 256 B
    unsigned short* sMuBf = (unsigned short*)(smem + 37888);    // 128 B
    float* sRedS  = (float*)smem;                               // epilogue alias (sA dead)
    float* sRedSS = (float*)(smem + 1024);

    const int tid = threadIdx.x;
    const int x0  = blockIdx.x * 64;
    const int y0  = blockIdx.y * 4;
    const int b   = blockIdx.z;
    const int w   = tid >> 6;
    const int l   = tid & 63;
    const int lm  = l & 15;
    const int g   = l >> 4;

    const unsigned short* wtb = NORM ? wt + (size_t)b * 4608 * 8 : wt;
    const float* biasb        = NORM ? bias + b * 64 : bias;

    if (NORM) {
        if (tid < 64) {
            float2 ms = stats_in[b * 64 + tid];
            unsigned short mb = f2bf(ms.x);
            sMuBf[tid]  = mb;
            sMaxMu[tid] = bf2f(mb);
        }
    }

    f32x4 acc[4][4];
#pragma unroll
    for (int fp = 0; fp < 4; ++fp)
#pragma unroll
        for (int fo = 0; fo < 4; ++fo)
            acc[fp][fo] = (f32x4){0.f, 0.f, 0.f, 0.f};

    for (int icc = 0; icc < ICC; ++icc) {
        __syncthreads();   // prior compute done (and stats init visible on first pass)

        // ---- stage A tile + halo for this icc ----
        if (NORM == 0) {
            for (int r = w; r < 6; r += 4) {
                int gy = y0 + r - 1;
                unsigned short* ldsrow = sA + r * 2112;
                if ((unsigned)gy < HH) {
                    const unsigned short* rowbase =
                        in_hwc + ((size_t)(b * HH + gy) * WW) * CIN + icc * 32;
#pragma unroll
                    for (int i = 0; i < 4; ++i) {
                        int u  = 4 + i * 64 + l;
                        int x  = u >> 2;
                        int cs = (u & 3) ^ ((x >> 1) & 3);
                        glds16(rowbase + (size_t)(x0 + x - 1) * CIN + cs * 8,
                               ldsrow + (size_t)(4 + i * 64) * 8);
                    }
                } else {
                    for (int u2 = l; u2 < 264; u2 += 64)
                        *(bf16x8*)(ldsrow + u2 * 8) = (bf16x8){0,0,0,0,0,0,0,0};
                }
            }
            if (tid < 48) {   // px slots 0 and 65 (swizzle identity there)
                int icq = tid & 3, side = (tid >> 2) & 1, r = tid >> 3;
                int xs = side ? 65 : 0;
                int gy = y0 + r - 1, gx = x0 + xs - 1;
                bf16x8 v = (bf16x8){0,0,0,0,0,0,0,0};
                if ((unsigned)gy < HH && (unsigned)gx < WW)
                    v = *(const bf16x8*)&in_hwc[(((size_t)(b * HH + gy) * WW) + gx) * CIN + icc * 32 + icq * 8];
                *(bf16x8*)&sA[(r * 264 + xs * 4 + icq) * 8] = v;
            }
        } else {
#pragma unroll
            for (int k = 0; k < 7; ++k) {
                int e = tid + k * 256;
                if (e < 1584) {
                    int r = e / 264, rem = e - r * 264;
                    int x = rem >> 2, icq = rem & 3;
                    int gy = y0 + r - 1, gx = x0 + x - 1;
                    int c0 = icc * 32 + icq * 8;
                    unsigned int w4[4];
                    if ((unsigned)gy < HH && (unsigned)gx < WW) {
                        bf16x8 v = *(const bf16x8*)&in_hwc[(((size_t)(b * HH + gy) * WW) + gx) * CIN + c0];
#pragma unroll
                        for (int jp = 0; jp < 4; ++jp) {
                            float f0 = fmaxf(bf2f(((unsigned short*)&v)[2 * jp]),     sMaxMu[c0 + 2 * jp]);
                            float f1 = fmaxf(bf2f(((unsigned short*)&v)[2 * jp + 1]), sMaxMu[c0 + 2 * jp + 1]);
                            w4[jp] = cvtpk(f0, f1);
                        }
                    } else {
#pragma unroll
                        for (int jp = 0; jp < 4; ++jp)
                            w4[jp] = (unsigned int)sMuBf[c0 + 2 * jp] |
                                     ((unsigned int)sMuBf[c0 + 2 * jp + 1] << 16);
                    }
                    *(uint4*)&sA[(r * 264 + x * 4 + (icq ^ ((x >> 1) & 3))) * 8] =
                        make_uint4(w4[0], w4[1], w4[2], w4[3]);
                }
            }
        }

        // ---- kt = ky rows: stage 3-kk weight slab, compute 3 taps ----
#pragma unroll
        for (int kt = 0; kt < 3; ++kt) {
            if (kt > 0) __syncthreads();     // previous compute done before sW overwrite
            {
                // wave-uniform LDS dest base + per-lane source (glds contract)
                const unsigned short* wsrc = wtb + ((size_t)icc * 2304 + kt * 768) * 8;
#pragma unroll
                for (int k = 0; k < 3; ++k)
                    glds16(wsrc + (size_t)(k * 256 + w * 64 + l) * 8,
                           sW + (size_t)(k * 256 + w * 64) * 8);
            }
            __syncthreads();                 // slab (and sA on kt==0) ready

            __builtin_amdgcn_s_setprio(1);
#pragma unroll
            for (int kx = 0; kx < 3; ++kx) {
                bf16x8 af[4], bfr[4];
#pragma unroll
                for (int fp = 0; fp < 4; ++fp) {
                    int xl = fp * 16 + lm + kx;
                    int u  = (xl * 4 + g) ^ ((xl >> 1) & 3);
                    af[fp] = *(const bf16x8*)&sA[((w + kt) * 264 + u) * 8];
                }
#pragma unroll
                for (int fo = 0; fo < 4; ++fo) {
                    int ocr = fo * 16 + lm;
                    int p   = (kx * 64 + ocr) * 4 + (g ^ ((ocr >> 1) & 3));
                    bfr[fo] = *(const bf16x8*)&sW[p * 8];
                }
#pragma unroll
                for (int fo = 0; fo < 4; ++fo)
#pragma unroll
                    for (int fp = 0; fp < 4; ++fp)
                        acc[fp][fo] = __builtin_amdgcn_mfma_f32_16x16x32_bf16(
                            bfr[fo], af[fp], acc[fp][fo], 0, 0, 0);
            }
            __builtin_amdgcn_s_setprio(0);
        }
    }

    __syncthreads();   // sA dead -> sRed alias safe

    // ---- epilogue: lane holds oc = 16*fo + 4g + j, px = x0 + 16*fp + lm ----
    const int row = y0 + w;
#pragma unroll
    for (int fo = 0; fo < 4; ++fo) {
        float4 b4 = *(const float4*)&biasb[fo * 16 + g * 4];
        float bb[4] = {b4.x, b4.y, b4.z, b4.w};
        float sj[4] = {0,0,0,0}, qj[4] = {0,0,0,0};
#pragma unroll
        for (int fp = 0; fp < 4; ++fp) {
            float v0 = acc[fp][fo][0] + bb[0], v1 = acc[fp][fo][1] + bb[1];
            float v2 = acc[fp][fo][2] + bb[2], v3 = acc[fp][fo][3] + bb[3];
            sj[0] += v0; qj[0] += v0 * v0;  sj[1] += v1; qj[1] += v1 * v1;
            sj[2] += v2; qj[2] += v2 * v2;  sj[3] += v3; qj[3] += v3 * v3;
            uint2 st = make_uint2(cvtpk(v0, v1), cvtpk(v2, v3));
            *(uint2*)&out_hwc[(((size_t)b * HH + row) * WW + x0 + fp * 16 + lm) * 64 + fo * 16 + g * 4] = st;
        }
#pragma unroll
        for (int m = 1; m <= 8; m <<= 1)
#pragma unroll
            for (int j = 0; j < 4; ++j) {
                sj[j] += __shfl_xor(sj[j], m);
                qj[j] += __shfl_xor(qj[j], m);
            }
        if (lm == 0) {
#pragma unroll
            for (int j = 0; j < 4; ++j) {
                sRedS [w * 64 + fo * 16 + g * 4 + j] = sj[j];
                sRedSS[w * 64 + fo * 16 + g * 4 + j] = qj[j];
            }
        }
    }
    __syncthreads();
    if (tid < 64) {
        float S = 0.f, SS = 0.f;
#pragma unroll
        for (int q = 0; q < 4; ++q) { S += sRedS[q * 64 + tid]; SS += sRedSS[q * 64 + tid]; }
        partials[((size_t)b * 400 + blockIdx.y * 5 + blockIdx.x) * 64 + tid] = make_float2(S, SS);
    }
}

// ---------------- partials -> (mean, rstd) ----------------
__global__ __launch_bounds__(256) void reduce_stats(const float2* __restrict__ partials,
                                                    float2* __restrict__ stats, int count)
{
    const int b  = blockIdx.x;
    const int oc = threadIdx.x & 63;
    const int q  = threadIdx.x >> 6;
    float s = 0.f, ss = 0.f;
    for (int i = q; i < count; i += 4) {
        float2 p = partials[((size_t)b * count + i) * 64 + oc];
        s += p.x; ss += p.y;
    }
    __shared__ float2 red[4][64];
    red[q][oc] = make_float2(s, ss);
    __syncthreads();
    if (threadIdx.x < 64) {
        float S = 0.f, SS = 0.f;
#pragma unroll
        for (int k = 0; k < 4; ++k) { S += red[k][threadIdx.x].x; SS += red[k][threadIdx.x].y; }
        const float n = (float)(HH * WW);
        float mean = S / n;
        float var  = fmaxf(SS / n - mean * mean, 0.f);
        stats[b * 64 + threadIdx.x] = make_float2(mean, rsqrtf(var + EPS));
    }
}

// ------- final: read h2 NHWC bf16, norm+relu, register-transpose, NCHW fp32 -------
__global__ __launch_bounds__(256) void finalize_t(const unsigned short* __restrict__ h2,
                                                  const float2* __restrict__ stats,
                                                  float* __restrict__ out)
{
    __shared__ float2 sSt[64];
    const int tid = threadIdx.x;
    const int b   = blockIdx.z;
    if (tid < 64) sSt[tid] = stats[b * 64 + tid];
    __syncthreads();
    const int r   = tid >> 6;
    const int px  = tid & 63;
    const int row = blockIdx.y * 4 + r;
    const int x   = blockIdx.x * 64 + px;
    const unsigned short* src = h2 + ((size_t)(b * HH + row) * WW + x) * 64;
    bf16x8 v[8];
#pragma unroll
    for (int cq = 0; cq < 8; ++cq) v[cq] = *(const bf16x8*)(src + cq * 8);
#pragma unroll
    for (int cq = 0; cq < 8; ++cq)
#pragma unroll
        for (int j = 0; j < 8; ++j) {
            int c = cq * 8 + j;
            float2 ms = sSt[c];
            float f = fmaxf((bf2f(((unsigned short*)&v[cq])[j]) - ms.x) * ms.y, 0.f);
            out[((size_t)(b * 64 + c) * HH + row) * WW + x] = f;
        }
}

extern "C" void kernel_launch(void* const* d_in, const int* in_sizes, int n_in,
                              void* d_out, int out_size, void* d_ws, size_t ws_size,
                              hipStream_t stream)
{
    const float* x  = (const float*)d_in[0];
    const float* w1 = (const float*)d_in[1];
    const float* b1 = (const float*)d_in[2];
    const float* w2 = (const float*)d_in[3];
    const float* b2 = (const float*)d_in[4];
    float* out = (float*)d_out;

    // ws layout (211,361,792 B, proven budget)
    char* ws = (char*)d_ws;
    unsigned short* h    = (unsigned short*)ws;                         // 105 MB NHWC bf16
    float2* partials     = (float2*)(ws + 104857600);                   // 1.6 MB
    float2* stats1       = (float2*)(ws + 104857600 + 1638400);
    float2* stats2       = (float2*)(ws + 104857600 + 1638400 + 4096);
    unsigned short* reg2 = (unsigned short*)(ws + 104857600 + 1638400 + 8192);
    unsigned short* x_hwc = reg2;   // 52 MB, dead after conv1
    unsigned short* h2    = reg2;   // 105 MB, conv2 output

    // weight scratch in tail of d_out (dead until finalize_t fully rewrites d_out last)
    // d_out = 209,715,200 B. bias2b needs 8*64*4 = 2048 B (r10 bug: had 1024 -> OOB).
    char* ob = (char*)d_out + 209715200;
    float*          bias2b = (float*)(ob - 2048);                          // 2048 B
    unsigned short* wt2b   = (unsigned short*)(ob - 2048 - 589824);        // 589,824 B
    unsigned short* wt2    = (unsigned short*)(ob - 2048 - 589824 - 73728);
    unsigned short* wt1    = (unsigned short*)(ob - 2048 - 589824 - 73728 - 36864);

    dim3 cgrid(5, 80, BB);

    wprep_swz<<<18, 256, 0, stream>>>(w1, w2, wt1, wt2);
    prep_hwc<<<dim3(5, HH, BB), 256, 0, stream>>>(x, x_hwc);

    // conv1: raw conv -> h (NHWC bf16) + stats partials
    conv_mfma<32, 0><<<cgrid, 256, 0, stream>>>(x_hwc, nullptr, wt1, b1, h, partials);
    reduce_stats<<<BB, 256, 0, stream>>>(partials, stats1, 400);
    // fold norm scale into per-batch conv2 weights + bias
    wfold<<<BB, 256, 0, stream>>>(wt2, b2, stats1, wt2b, bias2b);
    // conv2: staged max(h,mu) against folded weights -> h2 + partials
    conv_mfma<64, 1><<<cgrid, 256, 0, stream>>>(h, stats1, wt2b, bias2b, h2, partials);
    reduce_stats<<<BB, 256, 0, stream>>>(partials, stats2, 400);
    // norm(stats2)+relu + transpose -> d_out fp32 NCHW (fully rewrites d_out)
    finalize_t<<<dim3(5, 80, BB), 256, 0, stream>>>(h2, stats2, out);
}

// Round 12
// 365.542 us; speedup vs baseline: 1.1291x; 1.1291x over previous
//
#include <hip/hip_runtime.h>

#define HH 320
#define WW 320
#define BB 8
static constexpr float EPS = 1e-5f;

typedef __attribute__((ext_vector_type(8))) short bf16x8;
typedef __attribute__((ext_vector_type(4))) float f32x4;

__device__ inline float bf2f(unsigned short u) {
    union { unsigned int i; float f; } v; v.i = ((unsigned int)u) << 16; return v.f;
}
__device__ inline unsigned short f2bf(float f) {
    union { float f; unsigned int i; } v; v.f = f;
    unsigned int r = v.i + 0x7fffu + ((v.i >> 16) & 1u);
    return (unsigned short)(r >> 16);
}
__device__ inline unsigned int cvtpk(float a, float b) {   // lo16=bf16(a), hi16=bf16(b)
    unsigned int r;
    asm volatile("v_cvt_pk_bf16_f32 %0, %1, %2" : "=v"(r) : "v"(a), "v"(b));
    return r;
}
__device__ inline void glds16(const void* g, void* l) {
    __builtin_amdgcn_global_load_lds(
        (const __attribute__((address_space(1))) unsigned int*)g,
        (__attribute__((address_space(3))) unsigned int*)l, 16, 0, 0);
}

// ---------------- NCHW fp32 -> NHWC bf16 (CIN=32) ----------------
__global__ __launch_bounds__(256) void prep_hwc(const float* __restrict__ in,
                                                unsigned short* __restrict__ out)
{
    __shared__ float sT[32][65];
    const int tid = threadIdx.x;
    const int x0  = blockIdx.x * 64;
    const int y   = blockIdx.y;
    const int b   = blockIdx.z;
    for (int e = tid; e < 32 * 64; e += 256) {
        int c = e >> 6, x = e & 63;
        sT[c][x] = in[(((size_t)(b * 32 + c) * HH) + y) * WW + x0 + x];
    }
    __syncthreads();
    for (int e = tid; e < 64 * 32; e += 256) {
        int x = e >> 5, c = e & 31;
        out[((((size_t)b * HH + y) * WW) + x0 + x) * 32 + c] = f2bf(sT[c][x]);
    }
}

// ------ weights OIHW fp32 -> bank-swizzled bf16 glds-ready images ------
__global__ __launch_bounds__(256) void wprep_swz(const float* __restrict__ w1,
                                                 const float* __restrict__ w2,
                                                 unsigned short* __restrict__ wt1,
                                                 unsigned short* __restrict__ wt2)
{
    int i = blockIdx.x * 256 + threadIdx.x;
    if (i < 2304) {
        int s = i & 3, oc = (i >> 2) & 63, kk = i >> 8;
        int icq = s ^ ((oc >> 1) & 3);
        const float* src = w1 + ((size_t)oc * 32 + icq * 8) * 9 + kk;
        unsigned short pk[8];
#pragma unroll
        for (int j = 0; j < 8; ++j) pk[j] = f2bf(src[j * 9]);
        *(bf16x8*)&wt1[(size_t)i * 8] = *(bf16x8*)pk;
    }
    if (i < 4608) {
        int icc = i / 2304, u = i - icc * 2304;
        int s = u & 3, oc = (u >> 2) & 63, kk = u >> 8;
        int icq = s ^ ((oc >> 1) & 3);
        const float* src = w2 + ((size_t)oc * 64 + icc * 32 + icq * 8) * 9 + kk;
        unsigned short pk[8];
#pragma unroll
        for (int j = 0; j < 8; ++j) pk[j] = f2bf(src[j * 9]);
        *(bf16x8*)&wt2[(size_t)i * 8] = *(bf16x8*)pk;
    }
}

// ------ fold conv1 InstanceNorm scale into conv2 weights (per batch) ------
__global__ __launch_bounds__(256) void wfold(const unsigned short* __restrict__ wt2,
                                             const float* __restrict__ b2,
                                             const float2* __restrict__ stats1,
                                             unsigned short* __restrict__ wt2b,
                                             float* __restrict__ bias2b)
{
    __shared__ float sMu[64], sR[64];
    __shared__ float sBias[256];
    const int b = blockIdx.x, tid = threadIdx.x;
    if (tid < 64) {
        float2 ms = stats1[b * 64 + tid];
        sMu[tid] = bf2f(f2bf(ms.x));     // mu_bf, consistent with staged pads
        sR[tid]  = ms.y;
    }
    __syncthreads();
    const int oc = tid & 63, rep = tid >> 6;
    float bsum = 0.f;
    for (int cs = rep * 2; cs < rep * 2 + 2; ++cs) {
        int icc = cs >> 2, s = cs & 3;
        int icq = s ^ ((oc >> 1) & 3);
        for (int kk = 0; kk < 9; ++kk) {
            size_t u = (size_t)icc * 2304 + kk * 256 + oc * 4 + s;
            bf16x8 v = *(const bf16x8*)&wt2[u * 8];
            unsigned short o8[8];
#pragma unroll
            for (int j = 0; j < 8; ++j) {
                int ic = icc * 32 + icq * 8 + j;
                unsigned short wb = f2bf(bf2f(((unsigned short*)&v)[j]) * sR[ic]);
                o8[j] = wb;
                bsum += bf2f(wb) * sMu[ic];
            }
            *(bf16x8*)&wt2b[((size_t)b * 4608 + u) * 8] = *(bf16x8*)o8;
        }
    }
    sBias[tid] = bsum;
    __syncthreads();
    if (tid < 64) {
        float t = sBias[tid] + sBias[tid + 64] + sBias[tid + 128] + sBias[tid + 192];
        bias2b[b * 64 + tid] = b2[tid] - t;
    }
}

// ---------------- implicit-GEMM conv 3x3 via MFMA, 12-wave occupancy ----------------
// Block: 4 waves, wave w owns output row y0+w. Tile: 4 rows x 64 px x 64 oc.
// sW staged per ky-row (3 kk = 12.3 KB) -> LDS ~38 KB -> 3 blocks/CU (LDS 114 KB).
// (256,3): reg cap ~170/wave -> no spills (r11 lesson: (256,4) cap 128 < acc64+ops -> spilled).
// NORM=0 (conv1): sA via glds (pre-swizzled source), zero pads.
// NORM=1 (conv2): sA = bf16(max(h, mu_bf)) (scale folded into wt2b), pads = mu_bf.
template<int CIN, int NORM>
__global__ __launch_bounds__(256, 3) void conv_mfma(
    const unsigned short* __restrict__ in_hwc,   // [B][H][W][CIN] bf16
    const float2* __restrict__ stats_in,         // [B*64] (NORM)
    const unsigned short* __restrict__ wt,       // image; per-batch when NORM
    const float* __restrict__ bias,              // [64]; per-batch when NORM
    unsigned short* __restrict__ out_hwc,        // [B][H][W][64] bf16
    float2* __restrict__ partials)               // [B*400][64]
{
    constexpr int ICC = CIN / 32;

    __shared__ __align__(16) char smem[38912];
    unsigned short* sA    = (unsigned short*)smem;              // 25344 B
    unsigned short* sW    = (unsigned short*)(smem + 25344);    // 12288 B  [kx][oc][s]
    float*          sMaxMu= (float*)(smem + 37632);             // 256 B
    unsigned short* sMuBf = (unsigned short*)(smem + 37888);    // 128 B
    float* sRedS  = (float*)smem;                               // epilogue alias (sA dead)
    float* sRedSS = (float*)(smem + 1024);

    const int tid = threadIdx.x;
    const int x0  = blockIdx.x * 64;
    const int y0  = blockIdx.y * 4;
    const int b   = blockIdx.z;
    const int w   = tid >> 6;
    const int l   = tid & 63;
    const int lm  = l & 15;
    const int g   = l >> 4;

    const unsigned short* wtb = NORM ? wt + (size_t)b * 4608 * 8 : wt;
    const float* biasb        = NORM ? bias + b * 64 : bias;

    if (NORM) {
        if (tid < 64) {
            float2 ms = stats_in[b * 64 + tid];
            unsigned short mb = f2bf(ms.x);
            sMuBf[tid]  = mb;
            sMaxMu[tid] = bf2f(mb);
        }
    }

    f32x4 acc[4][4];
#pragma unroll
    for (int fp = 0; fp < 4; ++fp)
#pragma unroll
        for (int fo = 0; fo < 4; ++fo)
            acc[fp][fo] = (f32x4){0.f, 0.f, 0.f, 0.f};

    for (int icc = 0; icc < ICC; ++icc) {
        __syncthreads();   // prior compute done (and stats init visible on first pass)

        // ---- stage A tile + halo for this icc ----
        if (NORM == 0) {
            for (int r = w; r < 6; r += 4) {
                int gy = y0 + r - 1;
                unsigned short* ldsrow = sA + r * 2112;
                if ((unsigned)gy < HH) {
                    const unsigned short* rowbase =
                        in_hwc + ((size_t)(b * HH + gy) * WW) * CIN + icc * 32;
#pragma unroll
                    for (int i = 0; i < 4; ++i) {
                        int u  = 4 + i * 64 + l;
                        int x  = u >> 2;
                        int cs = (u & 3) ^ ((x >> 1) & 3);
                        glds16(rowbase + (size_t)(x0 + x - 1) * CIN + cs * 8,
                               ldsrow + (size_t)(4 + i * 64) * 8);
                    }
                } else {
                    for (int u2 = l; u2 < 264; u2 += 64)
                        *(bf16x8*)(ldsrow + u2 * 8) = (bf16x8){0,0,0,0,0,0,0,0};
                }
            }
            if (tid < 48) {   // px slots 0 and 65 (swizzle identity there)
                int icq = tid & 3, side = (tid >> 2) & 1, r = tid >> 3;
                int xs = side ? 65 : 0;
                int gy = y0 + r - 1, gx = x0 + xs - 1;
                bf16x8 v = (bf16x8){0,0,0,0,0,0,0,0};
                if ((unsigned)gy < HH && (unsigned)gx < WW)
                    v = *(const bf16x8*)&in_hwc[(((size_t)(b * HH + gy) * WW) + gx) * CIN + icc * 32 + icq * 8];
                *(bf16x8*)&sA[(r * 264 + xs * 4 + icq) * 8] = v;
            }
        } else {
#pragma unroll
            for (int k = 0; k < 7; ++k) {
                int e = tid + k * 256;
                if (e < 1584) {
                    int r = e / 264, rem = e - r * 264;
                    int x = rem >> 2, icq = rem & 3;
                    int gy = y0 + r - 1, gx = x0 + x - 1;
                    int c0 = icc * 32 + icq * 8;
                    unsigned int w4[4];
                    if ((unsigned)gy < HH && (unsigned)gx < WW) {
                        bf16x8 v = *(const bf16x8*)&in_hwc[(((size_t)(b * HH + gy) * WW) + gx) * CIN + c0];
#pragma unroll
                        for (int jp = 0; jp < 4; ++jp) {
                            float f0 = fmaxf(bf2f(((unsigned short*)&v)[2 * jp]),     sMaxMu[c0 + 2 * jp]);
                            float f1 = fmaxf(bf2f(((unsigned short*)&v)[2 * jp + 1]), sMaxMu[c0 + 2 * jp + 1]);
                            w4[jp] = cvtpk(f0, f1);
                        }
                    } else {
#pragma unroll
                        for (int jp = 0; jp < 4; ++jp)
                            w4[jp] = (unsigned int)sMuBf[c0 + 2 * jp] |
                                     ((unsigned int)sMuBf[c0 + 2 * jp + 1] << 16);
                    }
                    *(uint4*)&sA[(r * 264 + x * 4 + (icq ^ ((x >> 1) & 3))) * 8] =
                        make_uint4(w4[0], w4[1], w4[2], w4[3]);
                }
            }
        }

        // ---- kt = ky rows: stage 3-kk weight slab, compute 3 taps ----
#pragma unroll
        for (int kt = 0; kt < 3; ++kt) {
            if (kt > 0) __syncthreads();     // previous compute done before sW overwrite
            {
                // wave-uniform LDS dest base + per-lane source (glds contract)
                const unsigned short* wsrc = wtb + ((size_t)icc * 2304 + kt * 768) * 8;
#pragma unroll
                for (int k = 0; k < 3; ++k)
                    glds16(wsrc + (size_t)(k * 256 + w * 64 + l) * 8,
                           sW + (size_t)(k * 256 + w * 64) * 8);
            }
            __syncthreads();                 // slab (and sA on kt==0) ready

            __builtin_amdgcn_s_setprio(1);
#pragma unroll
            for (int kx = 0; kx < 3; ++kx) {
                bf16x8 af[4], bfr[4];
#pragma unroll
                for (int fp = 0; fp < 4; ++fp) {
                    int xl = fp * 16 + lm + kx;
                    int u  = (xl * 4 + g) ^ ((xl >> 1) & 3);
                    af[fp] = *(const bf16x8*)&sA[((w + kt) * 264 + u) * 8];
                }
#pragma unroll
                for (int fo = 0; fo < 4; ++fo) {
                    int ocr = fo * 16 + lm;
                    int p   = (kx * 64 + ocr) * 4 + (g ^ ((ocr >> 1) & 3));
                    bfr[fo] = *(const bf16x8*)&sW[p * 8];
                }
#pragma unroll
                for (int fo = 0; fo < 4; ++fo)
#pragma unroll
                    for (int fp = 0; fp < 4; ++fp)
                        acc[fp][fo] = __builtin_amdgcn_mfma_f32_16x16x32_bf16(
                            bfr[fo], af[fp], acc[fp][fo], 0, 0, 0);
            }
            __builtin_amdgcn_s_setprio(0);
        }
    }

    __syncthreads();   // sA dead -> sRed alias safe

    // ---- epilogue: lane holds oc = 16*fo + 4g + j, px = x0 + 16*fp + lm ----
    const int row = y0 + w;
#pragma unroll
    for (int fo = 0; fo < 4; ++fo) {
        float4 b4 = *(const float4*)&biasb[fo * 16 + g * 4];
        float bb[4] = {b4.x, b4.y, b4.z, b4.w};
        float sj[4] = {0,0,0,0}, qj[4] = {0,0,0,0};
#pragma unroll
        for (int fp = 0; fp < 4; ++fp) {
            float v0 = acc[fp][fo][0] + bb[0], v1 = acc[fp][fo][1] + bb[1];
            float v2 = acc[fp][fo][2] + bb[2], v3 = acc[fp][fo][3] + bb[3];
            sj[0] += v0; qj[0] += v0 * v0;  sj[1] += v1; qj[1] += v1 * v1;
            sj[2] += v2; qj[2] += v2 * v2;  sj[3] += v3; qj[3] += v3 * v3;
            uint2 st = make_uint2(cvtpk(v0, v1), cvtpk(v2, v3));
            *(uint2*)&out_hwc[(((size_t)b * HH + row) * WW + x0 + fp * 16 + lm) * 64 + fo * 16 + g * 4] = st;
        }
#pragma unroll
        for (int m = 1; m <= 8; m <<= 1)
#pragma unroll
            for (int j = 0; j < 4; ++j) {
                sj[j] += __shfl_xor(sj[j], m);
                qj[j] += __shfl_xor(qj[j], m);
            }
        if (lm == 0) {
#pragma unroll
            for (int j = 0; j < 4; ++j) {
                sRedS [w * 64 + fo * 16 + g * 4 + j] = sj[j];
                sRedSS[w * 64 + fo * 16 + g * 4 + j] = qj[j];
            }
        }
    }
    __syncthreads();
    if (tid < 64) {
        float S = 0.f, SS = 0.f;
#pragma unroll
        for (int q = 0; q < 4; ++q) { S += sRedS[q * 64 + tid]; SS += sRedSS[q * 64 + tid]; }
        partials[((size_t)b * 400 + blockIdx.y * 5 + blockIdx.x) * 64 + tid] = make_float2(S, SS);
    }
}

// ---------------- partials -> (mean, rstd) ----------------
__global__ __launch_bounds__(256) void reduce_stats(const float2* __restrict__ partials,
                                                    float2* __restrict__ stats, int count)
{
    const int b  = blockIdx.x;
    const int oc = threadIdx.x & 63;
    const int q  = threadIdx.x >> 6;
    float s = 0.f, ss = 0.f;
    for (int i = q; i < count; i += 4) {
        float2 p = partials[((size_t)b * count + i) * 64 + oc];
        s += p.x; ss += p.y;
    }
    __shared__ float2 red[4][64];
    red[q][oc] = make_float2(s, ss);
    __syncthreads();
    if (threadIdx.x < 64) {
        float S = 0.f, SS = 0.f;
#pragma unroll
        for (int k = 0; k < 4; ++k) { S += red[k][threadIdx.x].x; SS += red[k][threadIdx.x].y; }
        const float n = (float)(HH * WW);
        float mean = S / n;
        float var  = fmaxf(SS / n - mean * mean, 0.f);
        stats[b * 64 + threadIdx.x] = make_float2(mean, rsqrtf(var + EPS));
    }
}

// ------- final: read h2 NHWC bf16, norm+relu, register-transpose, NCHW fp32 -------
__global__ __launch_bounds__(256) void finalize_t(const unsigned short* __restrict__ h2,
                                                  const float2* __restrict__ stats,
                                                  float* __restrict__ out)
{
    __shared__ float2 sSt[64];
    const int tid = threadIdx.x;
    const int b   = blockIdx.z;
    if (tid < 64) sSt[tid] = stats[b * 64 + tid];
    __syncthreads();
    const int r   = tid >> 6;
    const int px  = tid & 63;
    const int row = blockIdx.y * 4 + r;
    const int x   = blockIdx.x * 64 + px;
    const unsigned short* src = h2 + ((size_t)(b * HH + row) * WW + x) * 64;
    bf16x8 v[8];
#pragma unroll
    for (int cq = 0; cq < 8; ++cq) v[cq] = *(const bf16x8*)(src + cq * 8);
#pragma unroll
    for (int cq = 0; cq < 8; ++cq)
#pragma unroll
        for (int j = 0; j < 8; ++j) {
            int c = cq * 8 + j;
            float2 ms = sSt[c];
            float f = fmaxf((bf2f(((unsigned short*)&v[cq])[j]) - ms.x) * ms.y, 0.f);
            out[((size_t)(b * 64 + c) * HH + row) * WW + x] = f;
        }
}

extern "C" void kernel_launch(void* const* d_in, const int* in_sizes, int n_in,
                              void* d_out, int out_size, void* d_ws, size_t ws_size,
                              hipStream_t stream)
{
    const float* x  = (const float*)d_in[0];
    const float* w1 = (const float*)d_in[1];
    const float* b1 = (const float*)d_in[2];
    const float* w2 = (const float*)d_in[3];
    const float* b2 = (const float*)d_in[4];
    float* out = (float*)d_out;

    // ws layout (211,361,792 B, proven budget)
    char* ws = (char*)d_ws;
    unsigned short* h    = (unsigned short*)ws;                         // 105 MB NHWC bf16
    float2* partials     = (float2*)(ws + 104857600);                   // 1.6 MB
    float2* stats1       = (float2*)(ws + 104857600 + 1638400);
    float2* stats2       = (float2*)(ws + 104857600 + 1638400 + 4096);
    unsigned short* reg2 = (unsigned short*)(ws + 104857600 + 1638400 + 8192);
    unsigned short* x_hwc = reg2;   // 52 MB, dead after conv1
    unsigned short* h2    = reg2;   // 105 MB, conv2 output

    // weight scratch in tail of d_out (dead until finalize_t fully rewrites d_out last)
    char* ob = (char*)d_out + 209715200;
    float*          bias2b = (float*)(ob - 2048);                          // 8*64*4 B
    unsigned short* wt2b   = (unsigned short*)(ob - 2048 - 589824);        // 589,824 B
    unsigned short* wt2    = (unsigned short*)(ob - 2048 - 589824 - 73728);
    unsigned short* wt1    = (unsigned short*)(ob - 2048 - 589824 - 73728 - 36864);

    dim3 cgrid(5, 80, BB);

    wprep_swz<<<18, 256, 0, stream>>>(w1, w2, wt1, wt2);
    prep_hwc<<<dim3(5, HH, BB), 256, 0, stream>>>(x, x_hwc);

    // conv1: raw conv -> h (NHWC bf16) + stats partials
    conv_mfma<32, 0><<<cgrid, 256, 0, stream>>>(x_hwc, nullptr, wt1, b1, h, partials);
    reduce_stats<<<BB, 256, 0, stream>>>(partials, stats1, 400);
    // fold norm scale into per-batch conv2 weights + bias
    wfold<<<BB, 256, 0, stream>>>(wt2, b2, stats1, wt2b, bias2b);
    // conv2: staged max(h,mu) against folded weights -> h2 + partials
    conv_mfma<64, 1><<<cgrid, 256, 0, stream>>>(h, stats1, wt2b, bias2b, h2, partials);
    reduce_stats<<<BB, 256, 0, stream>>>(partials, stats2, 400);
    // norm(stats2)+relu + transpose -> d_out fp32 NCHW (fully rewrites d_out)
    finalize_t<<<dim3(5, 80, BB), 256, 0, stream>>>(h2, stats2, out);
}

// Round 13
// 323.094 us; speedup vs baseline: 1.2775x; 1.1314x over previous
//
#include <hip/hip_runtime.h>

#define HH 320
#define WW 320
#define BB 8
static constexpr float EPS = 1e-5f;

typedef __attribute__((ext_vector_type(8))) short bf16x8;
typedef __attribute__((ext_vector_type(4))) float f32x4;

__device__ inline float bf2f(unsigned short u) {
    union { unsigned int i; float f; } v; v.i = ((unsigned int)u) << 16; return v.f;
}
__device__ inline unsigned short f2bf(float f) {
    union { float f; unsigned int i; } v; v.f = f;
    unsigned int r = v.i + 0x7fffu + ((v.i >> 16) & 1u);
    return (unsigned short)(r >> 16);
}
__device__ inline unsigned int cvtpk(float a, float b) {   // lo16=bf16(a), hi16=bf16(b)
    unsigned int r;
    asm volatile("v_cvt_pk_bf16_f32 %0, %1, %2" : "=v"(r) : "v"(a), "v"(b));
    return r;
}
__device__ inline void glds16(const void* g, void* l) {
    __builtin_amdgcn_global_load_lds(
        (const __attribute__((address_space(1))) unsigned int*)g,
        (__attribute__((address_space(3))) unsigned int*)l, 16, 0, 0);
}

// ---------------- NCHW fp32 -> NHWC bf16 (CIN=32) ----------------
__global__ __launch_bounds__(256) void prep_hwc(const float* __restrict__ in,
                                                unsigned short* __restrict__ out)
{
    __shared__ float sT[32][65];
    const int tid = threadIdx.x;
    const int x0  = blockIdx.x * 64;
    const int y   = blockIdx.y;
    const int b   = blockIdx.z;
    for (int e = tid; e < 32 * 64; e += 256) {
        int c = e >> 6, x = e & 63;
        sT[c][x] = in[(((size_t)(b * 32 + c) * HH) + y) * WW + x0 + x];
    }
    __syncthreads();
    for (int e = tid; e < 64 * 32; e += 256) {
        int x = e >> 5, c = e & 31;
        out[((((size_t)b * HH + y) * WW) + x0 + x) * 32 + c] = f2bf(sT[c][x]);
    }
}

// ------ weights OIHW fp32 -> bank-swizzled bf16 glds-ready images ------
__global__ __launch_bounds__(256) void wprep_swz(const float* __restrict__ w1,
                                                 const float* __restrict__ w2,
                                                 unsigned short* __restrict__ wt1,
                                                 unsigned short* __restrict__ wt2)
{
    int i = blockIdx.x * 256 + threadIdx.x;
    if (i < 2304) {
        int s = i & 3, oc = (i >> 2) & 63, kk = i >> 8;
        int icq = s ^ ((oc >> 1) & 3);
        const float* src = w1 + ((size_t)oc * 32 + icq * 8) * 9 + kk;
        unsigned short pk[8];
#pragma unroll
        for (int j = 0; j < 8; ++j) pk[j] = f2bf(src[j * 9]);
        *(bf16x8*)&wt1[(size_t)i * 8] = *(bf16x8*)pk;
    }
    if (i < 4608) {
        int icc = i / 2304, u = i - icc * 2304;
        int s = u & 3, oc = (u >> 2) & 63, kk = u >> 8;
        int icq = s ^ ((oc >> 1) & 3);
        const float* src = w2 + ((size_t)oc * 64 + icc * 32 + icq * 8) * 9 + kk;
        unsigned short pk[8];
#pragma unroll
        for (int j = 0; j < 8; ++j) pk[j] = f2bf(src[j * 9]);
        *(bf16x8*)&wt2[(size_t)i * 8] = *(bf16x8*)pk;
    }
}

// ------ fold conv1 InstanceNorm scale into conv2 weights (per batch) ------
__global__ __launch_bounds__(256) void wfold(const unsigned short* __restrict__ wt2,
                                             const float* __restrict__ b2,
                                             const float2* __restrict__ stats1,
                                             unsigned short* __restrict__ wt2b,
                                             float* __restrict__ bias2b)
{
    __shared__ float sMu[64], sR[64];
    __shared__ float sBias[256];
    const int b = blockIdx.x, tid = threadIdx.x;
    if (tid < 64) {
        float2 ms = stats1[b * 64 + tid];
        sMu[tid] = bf2f(f2bf(ms.x));     // mu_bf, consistent with staged pads
        sR[tid]  = ms.y;
    }
    __syncthreads();
    const int oc = tid & 63, rep = tid >> 6;
    float bsum = 0.f;
    for (int cs = rep * 2; cs < rep * 2 + 2; ++cs) {
        int icc = cs >> 2, s = cs & 3;
        int icq = s ^ ((oc >> 1) & 3);
        for (int kk = 0; kk < 9; ++kk) {
            size_t u = (size_t)icc * 2304 + kk * 256 + oc * 4 + s;
            bf16x8 v = *(const bf16x8*)&wt2[u * 8];
            unsigned short o8[8];
#pragma unroll
            for (int j = 0; j < 8; ++j) {
                int ic = icc * 32 + icq * 8 + j;
                unsigned short wb = f2bf(bf2f(((unsigned short*)&v)[j]) * sR[ic]);
                o8[j] = wb;
                bsum += bf2f(wb) * sMu[ic];
            }
            *(bf16x8*)&wt2b[((size_t)b * 4608 + u) * 8] = *(bf16x8*)o8;
        }
    }
    sBias[tid] = bsum;
    __syncthreads();
    if (tid < 64) {
        float t = sBias[tid] + sBias[tid + 64] + sBias[tid + 128] + sBias[tid + 192];
        bias2b[b * 64 + tid] = b2[tid] - t;
    }
}

// ---------- implicit-GEMM conv 3x3 via MFMA, supertile + 2-phase pipeline ----------
// Block: 4 waves; supertile = 4 y-subtiles (16 rows) x 64 px x 64 oc; 800 blocks.
// Steps s = (t, icc, kt): 48 MFMA each. sA double-buffered per (t,icc) group
// (issue at group start -> ~3 steps of latency cover); sW slab double-buffered
// per step. LDS 77.7 KB -> 2 blocks/CU at (256,2) (no spill: r11 lesson).
// NORM=0 (conv1): sA via glds, pre-swizzled source, zero pads.
// NORM=1 (conv2): T14 issue-early (group start) / transform+ds_write-late (group end);
//                 sA = bf16(max(h, mu_bf)); scale folded into wt2b; pads = mu_bf.
template<int CIN, int NORM>
__global__ __launch_bounds__(256, 2) void conv_mfma(
    const unsigned short* __restrict__ in_hwc,   // [B][H][W][CIN] bf16
    const float2* __restrict__ stats_in,         // [B*64] (NORM)
    const unsigned short* __restrict__ wt,       // image; per-batch when NORM
    const float* __restrict__ bias,              // [64]; per-batch when NORM
    unsigned short* __restrict__ out_hwc,        // [B][H][W][64] bf16
    float2* __restrict__ partials)               // [B*100][64]
{
    constexpr int ICC = CIN / 32;
    constexpr int NG  = 4 * ICC;      // (t,icc) groups
    constexpr int NS  = NG * 3;       // steps

    __shared__ __align__(16) unsigned short sA[2][6 * 264 * 8];   // 2 x 25344 B
    __shared__ __align__(16) unsigned short sWb[2][768 * 8];      // 2 x 12288 B
    __shared__ float sRedS[256];
    __shared__ float sRedSS[256];
    __shared__ float sMaxMu[64];
    __shared__ unsigned short sMuBf[64];

    const int tid = threadIdx.x;
    const int x0  = blockIdx.x * 64;
    const int yb  = blockIdx.y * 16;
    const int b   = blockIdx.z;
    const int w   = tid >> 6;
    const int l   = tid & 63;
    const int lm  = l & 15;
    const int g   = l >> 4;

    const unsigned short* wtb = NORM ? wt + (size_t)b * 4608 * 8 : wt;
    const float* biasb        = NORM ? bias + b * 64 : bias;

    if (NORM) {
        if (tid < 64) {
            float2 ms = stats_in[b * 64 + tid];
            unsigned short mb = f2bf(ms.x);
            sMuBf[tid]  = mb;
            sMaxMu[tid] = bf2f(mb);
        }
        __syncthreads();
    }

    // ---- weight slab stage: slab for step s2 -> sWb[buf] ----
    auto stage_slab = [&](int s2, int buf) {
        int kt2  = s2 % 3;
        int icc2 = (s2 / 3) % ICC;
        const unsigned short* wsrc = wtb + ((size_t)icc2 * 2304 + kt2 * 768) * 8;
        unsigned short* dst = &sWb[buf][0];
#pragma unroll
        for (int k = 0; k < 3; ++k)
            glds16(wsrc + (size_t)(k * 256 + w * 64 + l) * 8,
                   dst + (size_t)(k * 256 + w * 64) * 8);
    };

    // ---- sA group stage, NORM=0: glds (source pre-permuted for bank swizzle) ----
    auto issueA_glds = [&](int gi2) {
        int t2 = gi2 / ICC, icc2 = gi2 % ICC;
        int y02 = yb + t2 * 4;
        unsigned short* buf = &sA[gi2 & 1][0];
        for (int r = w; r < 6; r += 4) {
            int gy = y02 + r - 1;
            unsigned short* ldsrow = buf + r * 2112;
            if ((unsigned)gy < HH) {
                const unsigned short* rowbase =
                    in_hwc + ((size_t)(b * HH + gy) * WW) * CIN + icc2 * 32;
#pragma unroll
                for (int i = 0; i < 4; ++i) {
                    int u  = 4 + i * 64 + l;
                    int x  = u >> 2;
                    int cs = (u & 3) ^ ((x >> 1) & 3);
                    glds16(rowbase + (size_t)(x0 + x - 1) * CIN + cs * 8,
                           ldsrow + (size_t)(4 + i * 64) * 8);
                }
            } else {
                for (int u2 = l; u2 < 264; u2 += 64)
                    *(bf16x8*)(ldsrow + u2 * 8) = (bf16x8){0,0,0,0,0,0,0,0};
            }
        }
        if (tid < 48) {   // px slots 0 and 65 (swizzle identity there)
            int icq = tid & 3, side = (tid >> 2) & 1, r = tid >> 3;
            int xs = side ? 65 : 0;
            int gy = y02 + r - 1, gx = x0 + xs - 1;
            bf16x8 v = (bf16x8){0,0,0,0,0,0,0,0};
            if ((unsigned)gy < HH && (unsigned)gx < WW)
                v = *(const bf16x8*)&in_hwc[(((size_t)(b * HH + gy) * WW) + gx) * CIN + icc2 * 32 + icq * 8];
            *(bf16x8*)&buf[(r * 264 + xs * 4 + icq) * 8] = v;
        }
    };

    // ---- sA group stage, NORM=1: issue-early (loads only) / write-late ----
    bf16x8 ld[7];
    auto issueA_reg = [&](int gi2) {
        int t2 = gi2 / ICC, icc2 = gi2 % ICC;
        int y02 = yb + t2 * 4;
#pragma unroll
        for (int k = 0; k < 7; ++k) {
            int e = tid + k * 256;
            if (e < 1584) {
                int r = e / 264, rem = e - r * 264;
                int x = rem >> 2, icq = rem & 3;
                int gy = y02 + r - 1, gx = x0 + x - 1;
                if ((unsigned)gy < HH && (unsigned)gx < WW)
                    ld[k] = *(const bf16x8*)&in_hwc[(((size_t)(b * HH + gy) * WW) + gx) * CIN + icc2 * 32 + icq * 8];
            }
        }
    };
    auto writeA_reg = [&](int gi2) {
        int t2 = gi2 / ICC, icc2 = gi2 % ICC;
        int y02 = yb + t2 * 4;
        unsigned short* buf = &sA[gi2 & 1][0];
#pragma unroll
        for (int k = 0; k < 7; ++k) {
            int e = tid + k * 256;
            if (e < 1584) {
                int r = e / 264, rem = e - r * 264;
                int x = rem >> 2, icq = rem & 3;
                int gy = y02 + r - 1, gx = x0 + x - 1;
                int c0 = icc2 * 32 + icq * 8;
                unsigned int w4[4];
                if ((unsigned)gy < HH && (unsigned)gx < WW) {
#pragma unroll
                    for (int jp = 0; jp < 4; ++jp) {
                        float f0 = fmaxf(bf2f(((unsigned short*)&ld[k])[2 * jp]),     sMaxMu[c0 + 2 * jp]);
                        float f1 = fmaxf(bf2f(((unsigned short*)&ld[k])[2 * jp + 1]), sMaxMu[c0 + 2 * jp + 1]);
                        w4[jp] = cvtpk(f0, f1);
                    }
                } else {
#pragma unroll
                    for (int jp = 0; jp < 4; ++jp)
                        w4[jp] = (unsigned int)sMuBf[c0 + 2 * jp] |
                                 ((unsigned int)sMuBf[c0 + 2 * jp + 1] << 16);
                }
                *(uint4*)&buf[(r * 264 + x * 4 + (icq ^ ((x >> 1) & 3))) * 8] =
                    make_uint4(w4[0], w4[1], w4[2], w4[3]);
            }
        }
    };

    f32x4 acc[4][4];
#pragma unroll
    for (int fp = 0; fp < 4; ++fp)
#pragma unroll
        for (int fo = 0; fo < 4; ++fo)
            acc[fp][fo] = (f32x4){0.f, 0.f, 0.f, 0.f};

    float bb[4][4];
#pragma unroll
    for (int fo = 0; fo < 4; ++fo) {
        float4 b4 = *(const float4*)&biasb[fo * 16 + g * 4];
        bb[fo][0] = b4.x; bb[fo][1] = b4.y; bb[fo][2] = b4.z; bb[fo][3] = b4.w;
    }
    float sjA[4][4] = {}, qjA[4][4] = {};

    // ---- prologue ----
    stage_slab(0, 0);
    if (NORM == 0) {
        issueA_glds(0);
    } else {
        issueA_reg(0);
        writeA_reg(0);
    }
    __syncthreads();

    // ---- pipeline ----
    for (int s = 0; s < NS; ++s) {
        const int kt = s % 3;
        const int gi = s / 3;
        const int icc = gi % ICC;
        const int t  = gi / ICC;

        if (s + 1 < NS) stage_slab(s + 1, (s + 1) & 1);
        if (kt == 0 && gi + 1 < NG) {
            if (NORM == 0) issueA_glds(gi + 1);
            else           issueA_reg(gi + 1);
        }

        // ---- compute: 3 kx taps x 16 MFMA from sA[gi&1], sWb[s&1] ----
        {
            const unsigned short* bufA = &sA[gi & 1][0];
            const unsigned short* bufW = &sWb[s & 1][0];
            __builtin_amdgcn_s_setprio(1);
#pragma unroll
            for (int kx = 0; kx < 3; ++kx) {
                bf16x8 af[4], bfr[4];
#pragma unroll
                for (int fp = 0; fp < 4; ++fp) {
                    int xl = fp * 16 + lm + kx;
                    int u  = (xl * 4 + g) ^ ((xl >> 1) & 3);
                    af[fp] = *(const bf16x8*)(bufA + ((w + kt) * 264 + u) * 8);
                }
#pragma unroll
                for (int fo = 0; fo < 4; ++fo) {
                    int ocr = fo * 16 + lm;
                    int p   = (kx * 64 + ocr) * 4 + (g ^ ((ocr >> 1) & 3));
                    bfr[fo] = *(const bf16x8*)(bufW + p * 8);
                }
#pragma unroll
                for (int fo = 0; fo < 4; ++fo)
#pragma unroll
                    for (int fp = 0; fp < 4; ++fp)
                        acc[fp][fo] = __builtin_amdgcn_mfma_f32_16x16x32_bf16(
                            bfr[fo], af[fp], acc[fp][fo], 0, 0, 0);
            }
            __builtin_amdgcn_s_setprio(0);
        }

        // ---- subtile epilogue: stores + stats accumulation, reset acc ----
        if (kt == 2 && icc == ICC - 1) {
            const int row = yb + 4 * t + w;
#pragma unroll
            for (int fo = 0; fo < 4; ++fo) {
#pragma unroll
                for (int fp = 0; fp < 4; ++fp) {
                    float v0 = acc[fp][fo][0] + bb[fo][0], v1 = acc[fp][fo][1] + bb[fo][1];
                    float v2 = acc[fp][fo][2] + bb[fo][2], v3 = acc[fp][fo][3] + bb[fo][3];
                    sjA[fo][0] += v0; qjA[fo][0] += v0 * v0;
                    sjA[fo][1] += v1; qjA[fo][1] += v1 * v1;
                    sjA[fo][2] += v2; qjA[fo][2] += v2 * v2;
                    sjA[fo][3] += v3; qjA[fo][3] += v3 * v3;
                    uint2 st = make_uint2(cvtpk(v0, v1), cvtpk(v2, v3));
                    *(uint2*)&out_hwc[(((size_t)b * HH + row) * WW + x0 + fp * 16 + lm) * 64 + fo * 16 + g * 4] = st;
                    acc[fp][fo] = (f32x4){0.f, 0.f, 0.f, 0.f};
                }
            }
        }

        // ---- write-late of prefetched group (NORM only) ----
        if (NORM == 1 && kt == 2 && gi + 1 < NG) writeA_reg(gi + 1);

        __syncthreads();
    }

    // ---- block-level stats partial ----
#pragma unroll
    for (int fo = 0; fo < 4; ++fo) {
#pragma unroll
        for (int m = 1; m <= 8; m <<= 1)
#pragma unroll
            for (int j = 0; j < 4; ++j) {
                sjA[fo][j] += __shfl_xor(sjA[fo][j], m);
                qjA[fo][j] += __shfl_xor(qjA[fo][j], m);
            }
        if (lm == 0) {
#pragma unroll
            for (int j = 0; j < 4; ++j) {
                sRedS [w * 64 + fo * 16 + g * 4 + j] = sjA[fo][j];
                sRedSS[w * 64 + fo * 16 + g * 4 + j] = qjA[fo][j];
            }
        }
    }
    __syncthreads();
    if (tid < 64) {
        float S = 0.f, SS = 0.f;
#pragma unroll
        for (int q = 0; q < 4; ++q) { S += sRedS[q * 64 + tid]; SS += sRedSS[q * 64 + tid]; }
        partials[((size_t)b * 100 + blockIdx.y * 5 + blockIdx.x) * 64 + tid] = make_float2(S, SS);
    }
}

// ---------------- partials -> (mean, rstd) ----------------
__global__ __launch_bounds__(256) void reduce_stats(const float2* __restrict__ partials,
                                                    float2* __restrict__ stats, int count)
{
    const int b  = blockIdx.x;
    const int oc = threadIdx.x & 63;
    const int q  = threadIdx.x >> 6;
    float s = 0.f, ss = 0.f;
    for (int i = q; i < count; i += 4) {
        float2 p = partials[((size_t)b * count + i) * 64 + oc];
        s += p.x; ss += p.y;
    }
    __shared__ float2 red[4][64];
    red[q][oc] = make_float2(s, ss);
    __syncthreads();
    if (threadIdx.x < 64) {
        float S = 0.f, SS = 0.f;
#pragma unroll
        for (int k = 0; k < 4; ++k) { S += red[k][threadIdx.x].x; SS += red[k][threadIdx.x].y; }
        const float n = (float)(HH * WW);
        float mean = S / n;
        float var  = fmaxf(SS / n - mean * mean, 0.f);
        stats[b * 64 + threadIdx.x] = make_float2(mean, rsqrtf(var + EPS));
    }
}

// ------- final: read h2 NHWC bf16, norm+relu, register-transpose, NCHW fp32 -------
__global__ __launch_bounds__(256) void finalize_t(const unsigned short* __restrict__ h2,
                                                  const float2* __restrict__ stats,
                                                  float* __restrict__ out)
{
    __shared__ float2 sSt[64];
    const int tid = threadIdx.x;
    const int b   = blockIdx.z;
    if (tid < 64) sSt[tid] = stats[b * 64 + tid];
    __syncthreads();
    const int r   = tid >> 6;
    const int px  = tid & 63;
    const int row = blockIdx.y * 4 + r;
    const int x   = blockIdx.x * 64 + px;
    const unsigned short* src = h2 + ((size_t)(b * HH + row) * WW + x) * 64;
    bf16x8 v[8];
#pragma unroll
    for (int cq = 0; cq < 8; ++cq) v[cq] = *(const bf16x8*)(src + cq * 8);
#pragma unroll
    for (int cq = 0; cq < 8; ++cq)
#pragma unroll
        for (int j = 0; j < 8; ++j) {
            int c = cq * 8 + j;
            float2 ms = sSt[c];
            float f = fmaxf((bf2f(((unsigned short*)&v[cq])[j]) - ms.x) * ms.y, 0.f);
            out[((size_t)(b * 64 + c) * HH + row) * WW + x] = f;
        }
}

extern "C" void kernel_launch(void* const* d_in, const int* in_sizes, int n_in,
                              void* d_out, int out_size, void* d_ws, size_t ws_size,
                              hipStream_t stream)
{
    const float* x  = (const float*)d_in[0];
    const float* w1 = (const float*)d_in[1];
    const float* b1 = (const float*)d_in[2];
    const float* w2 = (const float*)d_in[3];
    const float* b2 = (const float*)d_in[4];
    float* out = (float*)d_out;

    // ws layout (211,361,792 B, proven budget)
    char* ws = (char*)d_ws;
    unsigned short* h    = (unsigned short*)ws;                         // 105 MB NHWC bf16
    float2* partials     = (float2*)(ws + 104857600);                   // 1.6 MB
    float2* stats1       = (float2*)(ws + 104857600 + 1638400);
    float2* stats2       = (float2*)(ws + 104857600 + 1638400 + 4096);
    unsigned short* reg2 = (unsigned short*)(ws + 104857600 + 1638400 + 8192);
    unsigned short* x_hwc = reg2;   // 52 MB, dead after conv1
    unsigned short* h2    = reg2;   // 105 MB, conv2 output

    // weight scratch in tail of d_out (dead until finalize_t fully rewrites d_out last)
    char* ob = (char*)d_out + 209715200;
    float*          bias2b = (float*)(ob - 2048);                          // 8*64*4 B
    unsigned short* wt2b   = (unsigned short*)(ob - 2048 - 589824);        // 589,824 B
    unsigned short* wt2    = (unsigned short*)(ob - 2048 - 589824 - 73728);
    unsigned short* wt1    = (unsigned short*)(ob - 2048 - 589824 - 73728 - 36864);

    dim3 cgrid(5, 20, BB);   // 64px x-tiles, 16-row supertiles, batch

    wprep_swz<<<18, 256, 0, stream>>>(w1, w2, wt1, wt2);
    prep_hwc<<<dim3(5, HH, BB), 256, 0, stream>>>(x, x_hwc);

    // conv1: raw conv -> h (NHWC bf16) + stats partials
    conv_mfma<32, 0><<<cgrid, 256, 0, stream>>>(x_hwc, nullptr, wt1, b1, h, partials);
    reduce_stats<<<BB, 256, 0, stream>>>(partials, stats1, 100);
    // fold norm scale into per-batch conv2 weights + bias
    wfold<<<BB, 256, 0, stream>>>(wt2, b2, stats1, wt2b, bias2b);
    // conv2: staged max(h,mu) against folded weights -> h2 + partials
    conv_mfma<64, 1><<<cgrid, 256, 0, stream>>>(h, stats1, wt2b, bias2b, h2, partials);
    reduce_stats<<<BB, 256, 0, stream>>>(partials, stats2, 100);
    // norm(stats2)+relu + transpose -> d_out fp32 NCHW (fully rewrites d_out)
    finalize_t<<<dim3(5, 80, BB), 256, 0, stream>>>(h2, stats2, out);
}